// Round 1
// baseline (172.786 us; speedup 1.0000x reference)
//
#include <hip/hip_runtime.h>
#include <math.h>

// Problem constants (from reference): N=50000, F=64, E=800000, C=32
#define NF 64
#define NC 32
#define BN_EPS 1e-3f

// ---------------------------------------------------------------------------
// Kernel 1: per-node transforms
//   y[n] = x[n] @ Wb            (Wb = W_edge[64:128])
//   z[n] = x[n] @ (Wt - Wb) + b (Wt = W_edge[0:64])
// thread = (node, channel); W staged interleaved in LDS so each thread reads
// (Wd, Wb) pairs as float2 (ds_read_b64, 2-way bank alias = free).
// ---------------------------------------------------------------------------
__global__ __launch_bounds__(256) void node_transform_kernel(
    const float* __restrict__ x, const float* __restrict__ W_edge,
    const float* __restrict__ b_edge, float* __restrict__ y,
    float* __restrict__ z, int N)
{
    __shared__ float WI[NF * NC * 2];  // [f][c][{Wt-Wb, Wb}]  16 KiB
    for (int i = threadIdx.x; i < NF * NC; i += 256) {
        float wt = W_edge[i];
        float wb = W_edge[NF * NC + i];
        WI[2 * i]     = wt - wb;
        WI[2 * i + 1] = wb;
    }
    __syncthreads();

    int idx = blockIdx.x * 256 + threadIdx.x;
    int n = idx >> 5, c = idx & 31;
    if (n >= N) return;

    const float4* xr = reinterpret_cast<const float4*>(x + (long)n * NF);
    float acc_y = 0.f, acc_z = 0.f;
#pragma unroll
    for (int f4 = 0; f4 < NF / 4; ++f4) {
        float4 xv = xr[f4];  // broadcast across the 32 lanes of this node
        int f = f4 * 4;
        float2 w;
        w = *reinterpret_cast<const float2*>(&WI[2 * ((f + 0) * NC + c)]);
        acc_z = fmaf(xv.x, w.x, acc_z); acc_y = fmaf(xv.x, w.y, acc_y);
        w = *reinterpret_cast<const float2*>(&WI[2 * ((f + 1) * NC + c)]);
        acc_z = fmaf(xv.y, w.x, acc_z); acc_y = fmaf(xv.y, w.y, acc_y);
        w = *reinterpret_cast<const float2*>(&WI[2 * ((f + 2) * NC + c)]);
        acc_z = fmaf(xv.z, w.x, acc_z); acc_y = fmaf(xv.z, w.y, acc_y);
        w = *reinterpret_cast<const float2*>(&WI[2 * ((f + 3) * NC + c)]);
        acc_z = fmaf(xv.w, w.x, acc_z); acc_y = fmaf(xv.w, w.y, acc_y);
    }
    y[(long)n * NC + c] = acc_y;
    z[(long)n * NC + c] = acc_z + b_edge[c];
}

// ---------------------------------------------------------------------------
// Kernel 2: edge scatter.  thread = (edge, channel).
//   hacc[r][c] += y[s][c];  deg[r] += 1 (channel-0 lane only)
// 32 consecutive lanes share one edge -> index loads broadcast, y reads are a
// coalesced 128B segment, atomics land in one 128B line.
// ---------------------------------------------------------------------------
__global__ __launch_bounds__(256) void edge_scatter_kernel(
    const int* __restrict__ senders, const int* __restrict__ receivers,
    const float* __restrict__ y, float* __restrict__ hacc,
    float* __restrict__ deg, int E)
{
    long idx = (long)blockIdx.x * 256 + threadIdx.x;
    int e = (int)(idx >> 5), c = (int)(idx & 31);
    if (e >= E) return;
    int s = senders[e];
    int r = receivers[e];
    atomicAdd(&hacc[(long)r * NC + c], y[(long)s * NC + c]);
    if (c == 0) atomicAdd(&deg[r], 1.0f);
}

// ---------------------------------------------------------------------------
// Kernel 3: finalize.  block = 256 threads = 256 nodes.
//   h = deg*z + hacc  ->  BN  ->  relu(h@W1+b1)  ->  sigmoid(@W2+b2)
// z/hacc read coalesced, transposed through padded LDS so each thread then
// walks its own row conflict-free.
// ---------------------------------------------------------------------------
__global__ __launch_bounds__(256) void finalize_kernel(
    const float* __restrict__ z, const float* __restrict__ hacc,
    const float* __restrict__ deg,
    const float* __restrict__ gamma, const float* __restrict__ beta,
    const float* __restrict__ mean, const float* __restrict__ var,
    const float* __restrict__ W1, const float* __restrict__ b1,
    const float* __restrict__ W2, const float* __restrict__ b2,
    float* __restrict__ out, int N)
{
    __shared__ float hrow[256][NC + 1];  // +1 pad: conflict-free row walk
    __shared__ float w1s[NC * 16];
    __shared__ float scale_s[NC], shift_s[NC], w2s[16], b1s[16];

    int t = threadIdx.x;
    if (t < NC) {
        float sc = gamma[t] * rsqrtf(var[t] + BN_EPS);
        scale_s[t] = sc;
        shift_s[t] = beta[t] - mean[t] * sc;
    }
    for (int i = t; i < NC * 16; i += 256) w1s[i] = W1[i];
    if (t < 16) { w2s[t] = W2[t]; b1s[t] = b1[t]; }

    long n0 = (long)blockIdx.x * 256;
#pragma unroll
    for (int i = 0; i < NC; ++i) {
        long j = (long)i * 256 + t;          // 0..8191 linear within block tile
        long g = n0 * NC + j;
        int row = (int)(j >> 5), col = (int)(j & 31);
        float v = 0.f;
        if (n0 + row < N) v = deg[n0 + row] * z[g] + hacc[g];
        hrow[row][col] = v;
    }
    __syncthreads();

    long n = n0 + t;
    if (n >= N) return;

    float acc[16];
#pragma unroll
    for (int k = 0; k < 16; ++k) acc[k] = b1s[k];
    for (int c = 0; c < NC; ++c) {
        float hb = fmaf(hrow[t][c], scale_s[c], shift_s[c]);
#pragma unroll
        for (int k = 0; k < 16; ++k) acc[k] = fmaf(hb, w1s[c * 16 + k], acc[k]);
    }
    float o = b2[0];
#pragma unroll
    for (int k = 0; k < 16; ++k) o = fmaf(fmaxf(acc[k], 0.f), w2s[k], o);
    out[n] = 1.f / (1.f + expf(-o));
}

// ---------------------------------------------------------------------------
extern "C" void kernel_launch(void* const* d_in, const int* in_sizes, int n_in,
                              void* d_out, int out_size, void* d_ws, size_t ws_size,
                              hipStream_t stream)
{
    const float* x         = (const float*)d_in[0];
    const int*   senders   = (const int*)  d_in[1];
    const int*   receivers = (const int*)  d_in[2];
    const float* W_edge    = (const float*)d_in[3];
    const float* b_edge    = (const float*)d_in[4];
    const float* gamma     = (const float*)d_in[5];
    const float* beta      = (const float*)d_in[6];
    const float* mov_mean  = (const float*)d_in[7];
    const float* mov_var   = (const float*)d_in[8];
    const float* W1        = (const float*)d_in[9];
    const float* b1        = (const float*)d_in[10];
    const float* W2        = (const float*)d_in[11];
    const float* b2        = (const float*)d_in[12];
    float* out = (float*)d_out;

    const int N = in_sizes[0] / NF;   // 50000
    const int E = in_sizes[1];        // 800000

    // workspace layout (floats): y[N*32] | z[N*32] | hacc[N*32] | deg[N]
    float* y    = (float*)d_ws;
    float* z    = y + (long)N * NC;
    float* hacc = z + (long)N * NC;
    float* deg  = hacc + (long)N * NC;

    // zero the accumulators (hacc + deg are contiguous)
    hipMemsetAsync(hacc, 0, (size_t)N * (NC + 1) * sizeof(float), stream);

    {   // kernel 1: y, z
        int threads = N * NC;
        int blocks = (threads + 255) / 256;
        node_transform_kernel<<<blocks, 256, 0, stream>>>(x, W_edge, b_edge, y, z, N);
    }
    {   // kernel 2: scatter
        long threads = (long)E * NC;
        int blocks = (int)((threads + 255) / 256);
        edge_scatter_kernel<<<blocks, 256, 0, stream>>>(senders, receivers, y, hacc, deg, E);
    }
    {   // kernel 3: finalize
        int blocks = (N + 255) / 256;
        finalize_kernel<<<blocks, 256, 0, stream>>>(z, hacc, deg, gamma, beta,
                                                    mov_mean, mov_var, W1, b1, W2, b2,
                                                    out, N);
    }
}

// Round 2
// 165.195 us; speedup vs baseline: 1.0460x; 1.0460x over previous
//
#include <hip/hip_runtime.h>
#include <math.h>

// Problem constants (from reference): N=50000, F=64, E=800000, C=32
#define NF 64
#define NC 32
#define BN_EPS 1e-3f

// ---------------------------------------------------------------------------
// Kernel 1: per-node transforms
//   y[n] = x[n] @ Wb            (Wb = W_edge[64:128])
//   z[n] = x[n] @ (Wt - Wb) + b (Wt = W_edge[0:64])
// ---------------------------------------------------------------------------
__global__ __launch_bounds__(256) void node_transform_kernel(
    const float* __restrict__ x, const float* __restrict__ W_edge,
    const float* __restrict__ b_edge, float* __restrict__ y,
    float* __restrict__ z, int N)
{
    __shared__ float WI[NF * NC * 2];  // [f][c][{Wt-Wb, Wb}]  16 KiB
    for (int i = threadIdx.x; i < NF * NC; i += 256) {
        float wt = W_edge[i];
        float wb = W_edge[NF * NC + i];
        WI[2 * i]     = wt - wb;
        WI[2 * i + 1] = wb;
    }
    __syncthreads();

    int idx = blockIdx.x * 256 + threadIdx.x;
    int n = idx >> 5, c = idx & 31;
    if (n >= N) return;

    const float4* xr = reinterpret_cast<const float4*>(x + (long)n * NF);
    float acc_y = 0.f, acc_z = 0.f;
#pragma unroll
    for (int f4 = 0; f4 < NF / 4; ++f4) {
        float4 xv = xr[f4];
        int f = f4 * 4;
        float2 w;
        w = *reinterpret_cast<const float2*>(&WI[2 * ((f + 0) * NC + c)]);
        acc_z = fmaf(xv.x, w.x, acc_z); acc_y = fmaf(xv.x, w.y, acc_y);
        w = *reinterpret_cast<const float2*>(&WI[2 * ((f + 1) * NC + c)]);
        acc_z = fmaf(xv.y, w.x, acc_z); acc_y = fmaf(xv.y, w.y, acc_y);
        w = *reinterpret_cast<const float2*>(&WI[2 * ((f + 2) * NC + c)]);
        acc_z = fmaf(xv.z, w.x, acc_z); acc_y = fmaf(xv.z, w.y, acc_y);
        w = *reinterpret_cast<const float2*>(&WI[2 * ((f + 3) * NC + c)]);
        acc_z = fmaf(xv.w, w.x, acc_z); acc_y = fmaf(xv.w, w.y, acc_y);
    }
    y[(long)n * NC + c] = acc_y;
    z[(long)n * NC + c] = acc_z + b_edge[c];
}

// ---------------------------------------------------------------------------
// CSR build: histogram -> block sums -> scan block sums -> offsets -> bucket
// ---------------------------------------------------------------------------
__global__ __launch_bounds__(256) void hist_kernel(
    const int* __restrict__ receivers, int* __restrict__ cnt, int E)
{
    int e = blockIdx.x * 256 + threadIdx.x;
    if (e < E) atomicAdd(&cnt[receivers[e]], 1);
}

__global__ __launch_bounds__(256) void block_sum_kernel(
    const int* __restrict__ cnt, int* __restrict__ bsum, int N)
{
    int i = blockIdx.x * 256 + threadIdx.x;
    int v = (i < N) ? cnt[i] : 0;
#pragma unroll
    for (int d = 32; d; d >>= 1) v += __shfl_down(v, d);
    __shared__ int ws[4];
    int lane = threadIdx.x & 63, w = threadIdx.x >> 6;
    if (lane == 0) ws[w] = v;
    __syncthreads();
    if (threadIdx.x == 0) bsum[blockIdx.x] = ws[0] + ws[1] + ws[2] + ws[3];
}

// exclusive-scan bsum in place (nb <= 256)
__global__ __launch_bounds__(256) void bsum_scan_kernel(int* __restrict__ bsum, int nb)
{
    __shared__ int l[256];
    int t = threadIdx.x;
    l[t] = (t < nb) ? bsum[t] : 0;
    __syncthreads();
    if (t == 0) {
        int run = 0;
        for (int i = 0; i < nb; ++i) { int v = l[i]; l[i] = run; run += v; }
    }
    __syncthreads();
    if (t < nb) bsum[t] = l[t];
}

__global__ __launch_bounds__(256) void offsets_kernel(
    const int* __restrict__ cnt, const int* __restrict__ bscan,
    int* __restrict__ off, int* __restrict__ cursor, int N)
{
    int i = blockIdx.x * 256 + threadIdx.x;
    int v = (i < N) ? cnt[i] : 0;
    int lane = threadIdx.x & 63, w = threadIdx.x >> 6;
    int incl = v;
#pragma unroll
    for (int d = 1; d < 64; d <<= 1) {
        int u = __shfl_up(incl, d);
        if (lane >= d) incl += u;
    }
    __shared__ int wsum[4];
    if (lane == 63) wsum[w] = incl;
    __syncthreads();
    int base = bscan[blockIdx.x];
    for (int j = 0; j < w; ++j) base += wsum[j];
    int excl = base + incl - v;
    if (i < N) {
        off[i] = excl;
        cursor[i] = excl;
        if (i == N - 1) off[N] = excl + v;
    }
}

__global__ __launch_bounds__(256) void bucket_kernel(
    const int* __restrict__ senders, const int* __restrict__ receivers,
    int* __restrict__ cursor, int* __restrict__ eidx, int E)
{
    int e = blockIdx.x * 256 + threadIdx.x;
    if (e >= E) return;
    int r = receivers[e];
    int pos = atomicAdd(&cursor[r], 1);
    eidx[pos] = senders[e];
}

// ---------------------------------------------------------------------------
// Kernel: gather-sum over incoming edges + BN + head + sigmoid, fused.
// Block = 256 threads = 8 nodes x 32 channels.
// ---------------------------------------------------------------------------
__global__ __launch_bounds__(256) void gather_finalize_kernel(
    const int* __restrict__ off, const int* __restrict__ eidx,
    const float* __restrict__ y, const float* __restrict__ z,
    const float* __restrict__ gamma, const float* __restrict__ beta,
    const float* __restrict__ mean, const float* __restrict__ var,
    const float* __restrict__ W1, const float* __restrict__ b1,
    const float* __restrict__ W2, const float* __restrict__ b2,
    float* __restrict__ out, int N)
{
    __shared__ float hbL[8][NC + 1];
    __shared__ float redL[8][16];
    __shared__ float w1s[NC * 16];
    __shared__ float scale_s[NC], shift_s[NC], w2s[16], b1s[16];

    int t = threadIdx.x;
    if (t < NC) {
        float sc = gamma[t] * rsqrtf(var[t] + BN_EPS);
        scale_s[t] = sc;
        shift_s[t] = beta[t] - mean[t] * sc;
    }
    for (int i = t; i < NC * 16; i += 256) w1s[i] = W1[i];
    if (t < 16) { w2s[t] = W2[t]; b1s[t] = b1[t]; }
    __syncthreads();

    int node = blockIdx.x * 8 + (t >> 5), c = t & 31;
    float hb = 0.f;
    if (node < N) {
        int o0 = off[node], o1 = off[node + 1];
        float acc = 0.f;
        int k = o0;
        for (; k + 1 < o1; k += 2) {
            int s0 = eidx[k], s1 = eidx[k + 1];
            float a0 = y[(long)s0 * NC + c];
            float a1 = y[(long)s1 * NC + c];
            acc += a0; acc += a1;
        }
        if (k < o1) acc += y[(long)eidx[k] * NC + c];
        float h = (float)(o1 - o0) * z[(long)node * NC + c] + acc;
        hb = fmaf(h, scale_s[c], shift_s[c]);
    }
    hbL[t >> 5][c] = hb;
    __syncthreads();

    if (t < 128) {
        int nd = t >> 4, k = t & 15;
        float a = b1s[k];
#pragma unroll
        for (int cc = 0; cc < NC; ++cc) a = fmaf(hbL[nd][cc], w1s[cc * 16 + k], a);
        redL[nd][k] = fmaxf(a, 0.f) * w2s[k];
    }
    __syncthreads();

    if (t < 8) {
        int n2 = blockIdx.x * 8 + t;
        if (n2 < N) {
            float o = b2[0];
#pragma unroll
            for (int k = 0; k < 16; ++k) o += redL[t][k];
            out[n2] = 1.f / (1.f + expf(-o));
        }
    }
}

// ---------------------------------------------------------------------------
extern "C" void kernel_launch(void* const* d_in, const int* in_sizes, int n_in,
                              void* d_out, int out_size, void* d_ws, size_t ws_size,
                              hipStream_t stream)
{
    const float* x         = (const float*)d_in[0];
    const int*   senders   = (const int*)  d_in[1];
    const int*   receivers = (const int*)  d_in[2];
    const float* W_edge    = (const float*)d_in[3];
    const float* b_edge    = (const float*)d_in[4];
    const float* gamma     = (const float*)d_in[5];
    const float* beta      = (const float*)d_in[6];
    const float* mov_mean  = (const float*)d_in[7];
    const float* mov_var   = (const float*)d_in[8];
    const float* W1        = (const float*)d_in[9];
    const float* b1        = (const float*)d_in[10];
    const float* W2        = (const float*)d_in[11];
    const float* b2        = (const float*)d_in[12];
    float* out = (float*)d_out;

    const int N = in_sizes[0] / NF;   // 50000
    const int E = in_sizes[1];        // 800000

    // workspace layout: y[N*32]f | z[N*32]f | cnt[N]i | off[N+1]i | cursor[N]i
    //                   | eidx[E]i | bsum[256]i    (~16.6 MB)
    float* y      = (float*)d_ws;
    float* z      = y + (long)N * NC;
    int*   cnt    = (int*)(z + (long)N * NC);
    int*   off    = cnt + N;
    int*   cursor = off + N + 1;
    int*   eidx   = cursor + N;
    int*   bsum   = eidx + E;

    const int nb = (N + 255) / 256;   // 196 (must be <= 256)

    hipMemsetAsync(cnt, 0, (size_t)N * sizeof(int), stream);

    node_transform_kernel<<<(N * NC + 255) / 256, 256, 0, stream>>>(
        x, W_edge, b_edge, y, z, N);

    hist_kernel<<<(E + 255) / 256, 256, 0, stream>>>(receivers, cnt, E);
    block_sum_kernel<<<nb, 256, 0, stream>>>(cnt, bsum, N);
    bsum_scan_kernel<<<1, 256, 0, stream>>>(bsum, nb);
    offsets_kernel<<<nb, 256, 0, stream>>>(cnt, bsum, off, cursor, N);
    bucket_kernel<<<(E + 255) / 256, 256, 0, stream>>>(senders, receivers, cursor, eidx, E);

    gather_finalize_kernel<<<(N + 7) / 8, 256, 0, stream>>>(
        off, eidx, y, z, gamma, beta, mov_mean, mov_var, W1, b1, W2, b2, out, N);
}